// Round 5
// baseline (153.444 us; speedup 1.0000x reference)
//
#include <hip/hip_runtime.h>

#define NHEAD 16
#define DHEAD 64
#define SEQ 2048
#define DMODEL 1024
#define BATCH 2
#define QSCALE 0.1803368801111204f  // 0.125 * log2(e): softmax runs in exp2 domain

typedef __bf16 bf16x8 __attribute__((ext_vector_type(8)));
typedef float f32x4 __attribute__((ext_vector_type(4)));
typedef float f32x16 __attribute__((ext_vector_type(16)));
typedef unsigned int u32x4 __attribute__((ext_vector_type(4)));

__device__ inline unsigned short f2bf(float f) {
  unsigned int u = __builtin_bit_cast(unsigned int, f);
  u = (u + 0x7FFFu + ((u >> 16) & 1u)) >> 16;
  return (unsigned short)u;
}

__device__ inline unsigned int cvtpk_bf16(float lo, float hi) {
  unsigned int r;
  asm("v_cvt_pk_bf16_f32 %0, %1, %2" : "=v"(r) : "v"(lo), "v"(hi));
  return r;
}

__device__ inline void pl32swap(unsigned int& a, unsigned int& b) {
  asm volatile("v_permlane32_swap_b32 %0, %1" : "+v"(a), "+v"(b));
}

typedef __attribute__((address_space(1))) unsigned int GU32;
typedef __attribute__((address_space(3))) unsigned int LU32;
__device__ inline void gld_lds16(const void* g, void* l) {
  __builtin_amdgcn_global_load_lds((GU32*)g, (LU32*)l, 16, 0, 0);
}

// ---------------- convert x to bf16 ----------------
__global__ __launch_bounds__(256) void k_conv_x(const float* __restrict__ x,
                                                unsigned short* __restrict__ xb) {
  int i = blockIdx.x * 256 + threadIdx.x;
  float4 v = ((const float4*)x)[i];
  ushort4 o;
  o.x = f2bf(v.x); o.y = f2bf(v.y); o.z = f2bf(v.z); o.w = f2bf(v.w);
  ((ushort4*)xb)[i] = o;
}

// ---------------- transpose weights to N-major bf16 ----------------
__global__ __launch_bounds__(256) void k_trans_w(const float* __restrict__ Wq, const float* __restrict__ Wk,
                                                 const float* __restrict__ Wv, const float* __restrict__ Wo,
                                                 unsigned short* __restrict__ Wqt, unsigned short* __restrict__ Wkt,
                                                 unsigned short* __restrict__ Wvt, unsigned short* __restrict__ Wot) {
  __shared__ float ts[64][65];
  int z = blockIdx.z;
  const float* src = (z == 0) ? Wq : (z == 1) ? Wk : (z == 2) ? Wv : Wo;
  unsigned short* dst = (z == 0) ? Wqt : (z == 1) ? Wkt : (z == 2) ? Wvt : Wot;
  int r0 = blockIdx.y * 64, c0 = blockIdx.x * 64;
  int t = threadIdx.x;
  int tr = t >> 4, tc = (t & 15) * 4;
#pragma unroll
  for (int i = 0; i < 4; i++) {
    int row = tr + i * 16;
    float4 v = *(const float4*)&src[(size_t)(r0 + row) * DMODEL + c0 + tc];
    ts[row][tc + 0] = v.x; ts[row][tc + 1] = v.y; ts[row][tc + 2] = v.z; ts[row][tc + 3] = v.w;
  }
  __syncthreads();
#pragma unroll
  for (int i = 0; i < 4; i++) {
    int nrow = tr + i * 16;
    ushort4 o;
    o.x = f2bf(ts[tc + 0][nrow]); o.y = f2bf(ts[tc + 1][nrow]);
    o.z = f2bf(ts[tc + 2][nrow]); o.w = f2bf(ts[tc + 3][nrow]);
    *(ushort4*)&dst[(size_t)(c0 + nrow) * DMODEL + r0 + tc] = o;
  }
}

// ---------------- GEMM core (m97-style) ----------------
__device__ inline void gemm_core(const unsigned short* __restrict__ A, const unsigned short* __restrict__ Bt,
                                 int brow0, int bcol0, unsigned short* As, unsigned short* Bs,
                                 f32x4 acc[4][4]) {
  int tid = threadIdx.x, lane = tid & 63, wave = tid >> 6;
  int wr = wave >> 1, wc = wave & 1;
  for (int kt = 0; kt < DMODEL / 32; ++kt) {
    int k0 = kt * 32;
    if (kt) __syncthreads();
#pragma unroll
    for (int qi = 0; qi < 2; ++qi) {
      int e0 = (wave * 2 + qi) * 512;
      int e = e0 + lane * 8;
      gld_lds16(&A[(size_t)(brow0 + (e >> 5)) * DMODEL + k0 + (e & 31)], &As[e0]);
      gld_lds16(&Bt[(size_t)(bcol0 + (e >> 5)) * DMODEL + k0 + (e & 31)], &Bs[e0]);
    }
    __syncthreads();
    bf16x8 af[4], bff[4];
#pragma unroll
    for (int i = 0; i < 4; i++)
      af[i] = *(const bf16x8*)&As[(wr * 64 + i * 16 + (lane & 15)) * 32 + (lane >> 4) * 8];
#pragma unroll
    for (int j = 0; j < 4; j++)
      bff[j] = *(const bf16x8*)&Bs[(wc * 64 + j * 16 + (lane & 15)) * 32 + (lane >> 4) * 8];
#pragma unroll
    for (int i = 0; i < 4; i++)
#pragma unroll
      for (int j = 0; j < 4; j++)
        acc[i][j] = __builtin_amdgcn_mfma_f32_16x16x32_bf16(af[i], bff[j], acc[i][j], 0, 0, 0);
  }
}

// ---------------- fused QKV projection ----------------
__global__ __launch_bounds__(256) void k_gemm_qkv(const unsigned short* __restrict__ xb,
                                                  const unsigned short* __restrict__ Wqt,
                                                  const unsigned short* __restrict__ Wkt,
                                                  const unsigned short* __restrict__ Wvt,
                                                  unsigned short* __restrict__ Qb,
                                                  unsigned short* __restrict__ Kb,
                                                  unsigned short* __restrict__ Vtb) {
  __shared__ unsigned short As[128 * 32];
  __shared__ unsigned short Bs[128 * 32];
  int bx = blockIdx.x;
  int wsel = bx >> 3;
  int col0 = (bx & 7) * 128;
  int brow0 = blockIdx.y * 128;
  const unsigned short* Bt = (wsel == 0) ? Wqt : (wsel == 1) ? Wkt : Wvt;
  int lane = threadIdx.x & 63, wave = threadIdx.x >> 6;
  int wr = wave >> 1, wc = wave & 1;
  f32x4 acc[4][4] = {};
  gemm_core(xb, Bt, brow0, col0, As, Bs, acc);
#pragma unroll
  for (int i = 0; i < 4; i++)
#pragma unroll
    for (int j = 0; j < 4; j++) {
      int rowb = brow0 + wr * 64 + i * 16 + ((lane >> 4) << 2);
      int c = col0 + wc * 64 + j * 16 + (lane & 15);
      int b = rowb >> 11, n0 = rowb & 2047;
      int h = c >> 6, d = c & 63;
      if (wsel == 2) {
        ushort4 o;
        o.x = f2bf(acc[i][j][0]); o.y = f2bf(acc[i][j][1]);
        o.z = f2bf(acc[i][j][2]); o.w = f2bf(acc[i][j][3]);
        *(ushort4*)&Vtb[((size_t)(b * NHEAD + h) * DHEAD + d) * SEQ + n0] = o;
      } else {
#pragma unroll
        for (int r = 0; r < 4; r++) {
          size_t idx = ((size_t)(b * NHEAD + h) * SEQ + (n0 + r)) * DHEAD + d;
          if (wsel == 0) Qb[idx] = f2bf(acc[i][j][r] * QSCALE);
          else           Kb[idx] = f2bf(acc[i][j][r]);
        }
      }
    }
}

// ---------------- flash attention (causal): 2 waves/block, no LDS, no barriers ----------------
// Q,K: [bh][n][64] bf16 (Q pre-scaled by 0.125*log2e); V: [bh][64][n]; Ob: [b][n][h*64]
__device__ __forceinline__ void attn_body(const bf16x8 (&KC)[8], const bf16x8 (&VC)[8],
                                          bf16x8 (&KN)[8], bf16x8 (&VN)[8],
                                          int cc, int nk,
                                          const unsigned short* __restrict__ Kh,
                                          const unsigned short* __restrict__ Vh,
                                          const bf16x8 (&qf)[4], int qrow, int h, int ql,
                                          f32x16& o0, f32x16& o1, float& m_r, float& l_r) {
  // prefetch next chunk into the other register set (issues early; waitcnt lands at next use)
  if (cc + 1 < nk) {
    const unsigned short* kp = Kh + (size_t)((cc + 1) * 64 + ql) * DHEAD + 8 * h;
#pragma unroll
    for (int ds = 0; ds < 4; ds++) {
      KN[ds]     = *(const bf16x8*)(kp + ds * 16);
      KN[4 + ds] = *(const bf16x8*)(kp + 32 * DHEAD + ds * 16);
    }
    const unsigned short* vp = Vh + (size_t)ql * SEQ + (cc + 1) * 64 + 8 * h;
#pragma unroll
    for (int ks = 0; ks < 4; ks++) {
      VN[ks]     = *(const bf16x8*)(vp + ks * 16);
      VN[4 + ks] = *(const bf16x8*)(vp + 32 * SEQ + ks * 16);
    }
  }
  // ---- S^T = K * Q^T ----
  f32x16 s0 = {}, s1 = {};
#pragma unroll
  for (int ds = 0; ds < 4; ds++) {
    s0 = __builtin_amdgcn_mfma_f32_32x32x16_bf16(KC[ds], qf[ds], s0, 0, 0, 0);
    s1 = __builtin_amdgcn_mfma_f32_32x32x16_bf16(KC[4 + ds], qf[ds], s1, 0, 0, 0);
  }
  int k0 = cc * 64;
  // ---- causal mask (diagonal chunk only) ----
  if (cc == nk - 1) {
#pragma unroll
    for (int r = 0; r < 16; r++) {
      int kloc = (r & 3) + 8 * (r >> 2) + 4 * h;
      if (k0 + kloc > qrow) s0[r] = -3.0e38f;
      if (k0 + 32 + kloc > qrow) s1[r] = -3.0e38f;
    }
  }
  // ---- online softmax (exp2 domain, defer-max THR=8; l_r kept as per-lane partial) ----
  float t0[8], t1[8];
#pragma unroll
  for (int r = 0; r < 8; r++) t0[r] = fmaxf(s0[r], s0[r + 8]);
#pragma unroll
  for (int r = 0; r < 8; r++) t1[r] = fmaxf(s1[r], s1[r + 8]);
#pragma unroll
  for (int r = 0; r < 4; r++) t0[r] = fmaxf(fmaxf(t0[r], t0[r + 4]), fmaxf(t1[r], t1[r + 4]));
  float pm = fmaxf(fmaxf(t0[0], t0[1]), fmaxf(t0[2], t0[3]));
  pm = fmaxf(pm, __shfl_xor(pm, 32));   // max must be synced across halves (shared P columns)
  bool grow = pm > m_r + 8.0f;
  float mnew = grow ? pm : m_r;
  float sf = grow ? __builtin_amdgcn_exp2f(m_r - mnew) : 1.0f;
  m_r = mnew;
  float rsum = 0.0f;
#pragma unroll
  for (int r = 0; r < 16; r++) { s0[r] = __builtin_amdgcn_exp2f(s0[r] - m_r); rsum += s0[r]; }
#pragma unroll
  for (int r = 0; r < 16; r++) { s1[r] = __builtin_amdgcn_exp2f(s1[r] - m_r); rsum += s1[r]; }
  l_r = l_r * sf + rsum;                // cross-half combine deferred to epilogue
  if (__ballot(grow)) {
#pragma unroll
    for (int r = 0; r < 16; r++) { o0[r] *= sf; o1[r] *= sf; }
  }
  // ---- P^T B-fragments in-register ----
  unsigned int pa0 = cvtpk_bf16(s0[0], s0[1]),   pa1 = cvtpk_bf16(s0[2], s0[3]);
  unsigned int pb0 = cvtpk_bf16(s0[4], s0[5]),   pb1 = cvtpk_bf16(s0[6], s0[7]);
  unsigned int pc0 = cvtpk_bf16(s0[8], s0[9]),   pc1 = cvtpk_bf16(s0[10], s0[11]);
  unsigned int pd0 = cvtpk_bf16(s0[12], s0[13]), pd1 = cvtpk_bf16(s0[14], s0[15]);
  unsigned int pe0 = cvtpk_bf16(s1[0], s1[1]),   pe1 = cvtpk_bf16(s1[2], s1[3]);
  unsigned int pf0 = cvtpk_bf16(s1[4], s1[5]),   pf1 = cvtpk_bf16(s1[6], s1[7]);
  unsigned int pg0 = cvtpk_bf16(s1[8], s1[9]),   pg1 = cvtpk_bf16(s1[10], s1[11]);
  unsigned int ph0 = cvtpk_bf16(s1[12], s1[13]), ph1 = cvtpk_bf16(s1[14], s1[15]);
  pl32swap(pa0, pb0); pl32swap(pa1, pb1);
  pl32swap(pc0, pd0); pl32swap(pc1, pd1);
  pl32swap(pe0, pf0); pl32swap(pe1, pf1);
  pl32swap(pg0, ph0); pl32swap(pg1, ph1);
  bf16x8 pfr[4];
  pfr[0] = __builtin_bit_cast(bf16x8, (u32x4){pa0, pa1, pb0, pb1});
  pfr[1] = __builtin_bit_cast(bf16x8, (u32x4){pc0, pc1, pd0, pd1});
  pfr[2] = __builtin_bit_cast(bf16x8, (u32x4){pe0, pe1, pf0, pf1});
  pfr[3] = __builtin_bit_cast(bf16x8, (u32x4){pg0, pg1, ph0, ph1});
  // ---- O^T += V^T * P^T ----
#pragma unroll
  for (int ks = 0; ks < 4; ks++) {
    o0 = __builtin_amdgcn_mfma_f32_32x32x16_bf16(VC[ks], pfr[ks], o0, 0, 0, 0);
    o1 = __builtin_amdgcn_mfma_f32_32x32x16_bf16(VC[4 + ks], pfr[ks], o1, 0, 0, 0);
  }
}

__global__ __launch_bounds__(128, 2) void k_attn(const unsigned short* __restrict__ Qb,
                                                 const unsigned short* __restrict__ Kb,
                                                 const unsigned short* __restrict__ Vtb,
                                                 unsigned short* __restrict__ Ob) {
  int id = blockIdx.x;                    // 1024 blocks x 2 waves: 8 waves/CU, 2/SIMD
  int eff = (id & 7) * 128 + (id >> 3);   // XCD-chunked: 4 bh per XCD L2
  int bh = eff >> 5;                      // 0..31
  int pr = eff & 31;                      // 0..31 -> pair {63-pr, pr} of 32-row q-tiles
  int tid = threadIdx.x;
  int wv = tid >> 6;                      // wave 0: heavy tile; wave 1: light tile
  int lane = tid & 63;
  int h = lane >> 5, ql = lane & 31;

  const unsigned short* Qh = Qb + (size_t)bh * SEQ * DHEAD;
  const unsigned short* Kh = Kb + (size_t)bh * SEQ * DHEAD;
  const unsigned short* Vh = Vtb + (size_t)bh * DHEAD * SEQ;
  int b = bh >> 4, hh = bh & 15;

  int v = wv ? pr : (63 - pr);
  int nk = (v >> 1) + 1;
  int qrow = v * 32 + ql;

  bf16x8 qf[4];
#pragma unroll
  for (int ds = 0; ds < 4; ds++)
    qf[ds] = *(const bf16x8*)&Qh[(size_t)qrow * DHEAD + ds * 16 + 8 * h];

  f32x16 o0 = {}, o1 = {};
  float m_r = -3.0e38f, l_r = 0.0f;

  bf16x8 KA[8], VA[8], KB[8], VB[8];
  {  // load chunk 0 into set A
    const unsigned short* kp = Kh + (size_t)ql * DHEAD + 8 * h;
#pragma unroll
    for (int ds = 0; ds < 4; ds++) {
      KA[ds]     = *(const bf16x8*)(kp + ds * 16);
      KA[4 + ds] = *(const bf16x8*)(kp + 32 * DHEAD + ds * 16);
    }
    const unsigned short* vp = Vh + (size_t)ql * SEQ + 8 * h;
#pragma unroll
    for (int ks = 0; ks < 4; ks++) {
      VA[ks]     = *(const bf16x8*)(vp + ks * 16);
      VA[4 + ks] = *(const bf16x8*)(vp + 32 * SEQ + ks * 16);
    }
  }
#pragma unroll 1
  for (int c = 0; c < nk; c += 2) {
    attn_body(KA, VA, KB, VB, c, nk, Kh, Vh, qf, qrow, h, ql, o0, o1, m_r, l_r);
    if (c + 1 < nk)
      attn_body(KB, VB, KA, VA, c + 1, nk, Kh, Vh, qf, qrow, h, ql, o0, o1, m_r, l_r);
  }

  // ---- epilogue: combine cross-half l, then O = O^T / l ----
  float lt = l_r + __shfl_xor(l_r, 32);
  float rl = 1.0f / lt;
  size_t obase = ((size_t)(b * SEQ + qrow)) * DMODEL + hh * DHEAD;
#pragma unroll
  for (int rg = 0; rg < 4; rg++) {
    uint2 w0, w1;
    w0.x = cvtpk_bf16(o0[4 * rg] * rl, o0[4 * rg + 1] * rl);
    w0.y = cvtpk_bf16(o0[4 * rg + 2] * rl, o0[4 * rg + 3] * rl);
    w1.x = cvtpk_bf16(o1[4 * rg] * rl, o1[4 * rg + 1] * rl);
    w1.y = cvtpk_bf16(o1[4 * rg + 2] * rl, o1[4 * rg + 3] * rl);
    *(uint2*)&Ob[obase + 8 * rg + 4 * h] = w0;
    *(uint2*)&Ob[obase + 32 + 8 * rg + 4 * h] = w1;
  }
}

// ---------------- output projection ----------------
__global__ __launch_bounds__(256) void k_gemm_out(const unsigned short* __restrict__ Ob,
                                                  const unsigned short* __restrict__ Wot,
                                                  float* __restrict__ out) {
  __shared__ unsigned short As[128 * 32];
  __shared__ unsigned short Bs[128 * 32];
  int col0 = blockIdx.x * 128;
  int brow0 = blockIdx.y * 128;
  int lane = threadIdx.x & 63, wave = threadIdx.x >> 6;
  int wr = wave >> 1, wc = wave & 1;
  f32x4 acc[4][4] = {};
  gemm_core(Ob, Wot, brow0, col0, As, Bs, acc);
#pragma unroll
  for (int i = 0; i < 4; i++)
#pragma unroll
    for (int j = 0; j < 4; j++)
#pragma unroll
      for (int r = 0; r < 4; r++) {
        int row = brow0 + wr * 64 + i * 16 + ((lane >> 4) << 2) + r;
        int c = col0 + wc * 64 + j * 16 + (lane & 15);
        out[(size_t)row * DMODEL + c] = acc[i][j][r];
      }
}

extern "C" void kernel_launch(void* const* d_in, const int* in_sizes, int n_in,
                              void* d_out, int out_size, void* d_ws, size_t ws_size,
                              hipStream_t stream) {
  const float* x  = (const float*)d_in[0];
  const float* Wq = (const float*)d_in[1];
  const float* Wk = (const float*)d_in[2];
  const float* Wv = (const float*)d_in[3];
  const float* Wo = (const float*)d_in[4];
  float* out = (float*)d_out;
  char* ws = (char*)d_ws;
  unsigned short* xb  = (unsigned short*)(ws);
  unsigned short* Wqt = (unsigned short*)(ws + (8ull << 20));
  unsigned short* Wkt = (unsigned short*)(ws + (10ull << 20));
  unsigned short* Wvt = (unsigned short*)(ws + (12ull << 20));
  unsigned short* Wot = (unsigned short*)(ws + (14ull << 20));
  unsigned short* Qb  = (unsigned short*)(ws + (16ull << 20));
  unsigned short* Kb  = (unsigned short*)(ws + (24ull << 20));
  unsigned short* Vtb = (unsigned short*)(ws + (32ull << 20));
  unsigned short* Ob  = (unsigned short*)(ws + (40ull << 20));

  k_conv_x<<<dim3(4096), dim3(256), 0, stream>>>(x, xb);
  k_trans_w<<<dim3(16, 16, 4), dim3(256), 0, stream>>>(Wq, Wk, Wv, Wo, Wqt, Wkt, Wvt, Wot);
  k_gemm_qkv<<<dim3(24, 32), dim3(256), 0, stream>>>(xb, Wqt, Wkt, Wvt, Qb, Kb, Vtb);
  k_attn<<<dim3(1024), dim3(128), 0, stream>>>(Qb, Kb, Vtb, Ob);
  k_gemm_out<<<dim3(8, 32), dim3(256), 0, stream>>>(Ob, Wot, out);
}

// Round 6
// 136.059 us; speedup vs baseline: 1.1278x; 1.1278x over previous
//
#include <hip/hip_runtime.h>

#define NHEAD 16
#define DHEAD 64
#define SEQ 2048
#define DMODEL 1024
#define BATCH 2
#define QSCALE 0.1803368801111204f  // 0.125 * log2(e): softmax runs in exp2 domain

typedef __bf16 bf16x8 __attribute__((ext_vector_type(8)));
typedef float f32x4 __attribute__((ext_vector_type(4)));
typedef float f32x16 __attribute__((ext_vector_type(16)));
typedef unsigned int u32x4 __attribute__((ext_vector_type(4)));

__device__ inline unsigned short f2bf(float f) {
  unsigned int u = __builtin_bit_cast(unsigned int, f);
  u = (u + 0x7FFFu + ((u >> 16) & 1u)) >> 16;
  return (unsigned short)u;
}

__device__ inline unsigned int cvtpk_bf16(float lo, float hi) {
  unsigned int r;
  asm("v_cvt_pk_bf16_f32 %0, %1, %2" : "=v"(r) : "v"(lo), "v"(hi));
  return r;
}

__device__ inline void pl32swap(unsigned int& a, unsigned int& b) {
  asm volatile("v_permlane32_swap_b32 %0, %1" : "+v"(a), "+v"(b));
}

typedef __attribute__((address_space(1))) unsigned int GU32;
typedef __attribute__((address_space(3))) unsigned int LU32;
__device__ inline void gld_lds16(const void* g, void* l) {
  __builtin_amdgcn_global_load_lds((GU32*)g, (LU32*)l, 16, 0, 0);
}

// ---------------- convert x to bf16 ----------------
__global__ __launch_bounds__(256) void k_conv_x(const float* __restrict__ x,
                                                unsigned short* __restrict__ xb) {
  int i = blockIdx.x * 256 + threadIdx.x;
  float4 v = ((const float4*)x)[i];
  ushort4 o;
  o.x = f2bf(v.x); o.y = f2bf(v.y); o.z = f2bf(v.z); o.w = f2bf(v.w);
  ((ushort4*)xb)[i] = o;
}

// ---------------- transpose weights to N-major bf16 ----------------
__global__ __launch_bounds__(256) void k_trans_w(const float* __restrict__ Wq, const float* __restrict__ Wk,
                                                 const float* __restrict__ Wv, const float* __restrict__ Wo,
                                                 unsigned short* __restrict__ Wqt, unsigned short* __restrict__ Wkt,
                                                 unsigned short* __restrict__ Wvt, unsigned short* __restrict__ Wot) {
  __shared__ float ts[64][65];
  int z = blockIdx.z;
  const float* src = (z == 0) ? Wq : (z == 1) ? Wk : (z == 2) ? Wv : Wo;
  unsigned short* dst = (z == 0) ? Wqt : (z == 1) ? Wkt : (z == 2) ? Wvt : Wot;
  int r0 = blockIdx.y * 64, c0 = blockIdx.x * 64;
  int t = threadIdx.x;
  int tr = t >> 4, tc = (t & 15) * 4;
#pragma unroll
  for (int i = 0; i < 4; i++) {
    int row = tr + i * 16;
    float4 v = *(const float4*)&src[(size_t)(r0 + row) * DMODEL + c0 + tc];
    ts[row][tc + 0] = v.x; ts[row][tc + 1] = v.y; ts[row][tc + 2] = v.z; ts[row][tc + 3] = v.w;
  }
  __syncthreads();
#pragma unroll
  for (int i = 0; i < 4; i++) {
    int nrow = tr + i * 16;
    ushort4 o;
    o.x = f2bf(ts[tc + 0][nrow]); o.y = f2bf(ts[tc + 1][nrow]);
    o.z = f2bf(ts[tc + 2][nrow]); o.w = f2bf(ts[tc + 3][nrow]);
    *(ushort4*)&dst[(size_t)(c0 + nrow) * DMODEL + r0 + tc] = o;
  }
}

// ---------------- GEMM core (m97-style) ----------------
__device__ inline void gemm_core(const unsigned short* __restrict__ A, const unsigned short* __restrict__ Bt,
                                 int brow0, int bcol0, unsigned short* As, unsigned short* Bs,
                                 f32x4 acc[4][4]) {
  int tid = threadIdx.x, lane = tid & 63, wave = tid >> 6;
  int wr = wave >> 1, wc = wave & 1;
  for (int kt = 0; kt < DMODEL / 32; ++kt) {
    int k0 = kt * 32;
    if (kt) __syncthreads();
#pragma unroll
    for (int qi = 0; qi < 2; ++qi) {
      int e0 = (wave * 2 + qi) * 512;
      int e = e0 + lane * 8;
      gld_lds16(&A[(size_t)(brow0 + (e >> 5)) * DMODEL + k0 + (e & 31)], &As[e0]);
      gld_lds16(&Bt[(size_t)(bcol0 + (e >> 5)) * DMODEL + k0 + (e & 31)], &Bs[e0]);
    }
    __syncthreads();
    bf16x8 af[4], bff[4];
#pragma unroll
    for (int i = 0; i < 4; i++)
      af[i] = *(const bf16x8*)&As[(wr * 64 + i * 16 + (lane & 15)) * 32 + (lane >> 4) * 8];
#pragma unroll
    for (int j = 0; j < 4; j++)
      bff[j] = *(const bf16x8*)&Bs[(wc * 64 + j * 16 + (lane & 15)) * 32 + (lane >> 4) * 8];
#pragma unroll
    for (int i = 0; i < 4; i++)
#pragma unroll
      for (int j = 0; j < 4; j++)
        acc[i][j] = __builtin_amdgcn_mfma_f32_16x16x32_bf16(af[i], bff[j], acc[i][j], 0, 0, 0);
  }
}

// ---------------- fused QKV projection ----------------
__global__ __launch_bounds__(256) void k_gemm_qkv(const unsigned short* __restrict__ xb,
                                                  const unsigned short* __restrict__ Wqt,
                                                  const unsigned short* __restrict__ Wkt,
                                                  const unsigned short* __restrict__ Wvt,
                                                  unsigned short* __restrict__ Qb,
                                                  unsigned short* __restrict__ Kb,
                                                  unsigned short* __restrict__ Vtb) {
  __shared__ unsigned short As[128 * 32];
  __shared__ unsigned short Bs[128 * 32];
  int bx = blockIdx.x;
  int wsel = bx >> 3;
  int col0 = (bx & 7) * 128;
  int brow0 = blockIdx.y * 128;
  const unsigned short* Bt = (wsel == 0) ? Wqt : (wsel == 1) ? Wkt : Wvt;
  int lane = threadIdx.x & 63, wave = threadIdx.x >> 6;
  int wr = wave >> 1, wc = wave & 1;
  f32x4 acc[4][4] = {};
  gemm_core(xb, Bt, brow0, col0, As, Bs, acc);
#pragma unroll
  for (int i = 0; i < 4; i++)
#pragma unroll
    for (int j = 0; j < 4; j++) {
      int rowb = brow0 + wr * 64 + i * 16 + ((lane >> 4) << 2);
      int c = col0 + wc * 64 + j * 16 + (lane & 15);
      int b = rowb >> 11, n0 = rowb & 2047;
      int h = c >> 6, d = c & 63;
      if (wsel == 2) {
        ushort4 o;
        o.x = f2bf(acc[i][j][0]); o.y = f2bf(acc[i][j][1]);
        o.z = f2bf(acc[i][j][2]); o.w = f2bf(acc[i][j][3]);
        *(ushort4*)&Vtb[((size_t)(b * NHEAD + h) * DHEAD + d) * SEQ + n0] = o;
      } else {
#pragma unroll
        for (int r = 0; r < 4; r++) {
          size_t idx = ((size_t)(b * NHEAD + h) * SEQ + (n0 + r)) * DHEAD + d;
          if (wsel == 0) Qb[idx] = f2bf(acc[i][j][r] * QSCALE);
          else           Kb[idx] = f2bf(acc[i][j][r]);
        }
      }
    }
}

// ---------------- flash attention (causal): 2-wave blocks, coalesced LDS staging ----------------
// Q,K: [bh][n][64] bf16 (Q pre-scaled by 0.125*log2e); V: [bh][64][n]; Ob: [b][n][h*64]
// wave0 = heavy tile (63-pr), wave1 = light tile (pr): light's chunk range nests in heavy's,
// so one staged K/V stream serves both. 1024 blocks, 4 blocks/CU, 8 waves/CU.
#define KPAD 68
__global__ __launch_bounds__(128, 2) void k_attn(const unsigned short* __restrict__ Qb,
                                                 const unsigned short* __restrict__ Kb,
                                                 const unsigned short* __restrict__ Vtb,
                                                 unsigned short* __restrict__ Ob) {
  __shared__ unsigned short Ks[2][64 * KPAD];  // [k][d], stride 68 (2-way conflicts = free)
  __shared__ unsigned short Vs[2][64 * KPAD];  // [d][k]
  int id = blockIdx.x;
  int xcd = id & 7, loc = id >> 3;        // 4 bh per XCD -> K+V 2MB inside one L2
  int bh2 = loc >> 5, jj = loc & 31;
  int bh = xcd * 4 + bh2;
  int pr = (jj + bh2 * 8) & 31;           // stripes per-CU load under either dispatch order
  int tid = threadIdx.x, wv = tid >> 6, lane = tid & 63;
  int h = lane >> 5, ql = lane & 31;
  int v = wv ? pr : (63 - pr);            // per-wave q-tile (32 rows)
  int dcn = v >> 1;                       // wave's diagonal chunk
  int nk = ((63 - pr) >> 1) + 1;          // block chunk count (heavy wave's range)
  int qrow = v * 32 + ql;
  int sr = tid >> 3, sc = (tid & 7) * 8;  // staging: 8 threads per 128-B row, fully coalesced

  const unsigned short* Qh = Qb + (size_t)bh * SEQ * DHEAD;
  const unsigned short* Kh = Kb + (size_t)bh * SEQ * DHEAD;
  const unsigned short* Vh = Vtb + (size_t)bh * DHEAD * SEQ;
  int b = bh >> 4, hh = bh & 15;

  bf16x8 qf[4];
#pragma unroll
  for (int ds = 0; ds < 4; ds++)
    qf[ds] = *(const bf16x8*)&Qh[(size_t)qrow * DHEAD + ds * 16 + 8 * h];

  f32x16 o0 = {}, o1 = {};
  float m_r = -3.0e38f, l_r = 0.0f;

  // stage chunk 0 -> buf 0 (coalesced)
#pragma unroll
  for (int rj = 0; rj < 4; rj++) {
    int row = rj * 16 + sr;
    *(bf16x8*)&Ks[0][row * KPAD + sc] = *(const bf16x8*)&Kh[(size_t)row * DHEAD + sc];
    *(bf16x8*)&Vs[0][row * KPAD + sc] = *(const bf16x8*)&Vh[(size_t)row * SEQ + sc];
  }
  __syncthreads();

#pragma unroll 1
  for (int kc = 0; kc < nk; ++kc) {
    int cur = kc & 1;
    bool pfn = (kc + 1 < nk);
    bf16x8 kpre[4], vpre[4];
    if (pfn) {  // coalesced register prefetch of chunk kc+1
      int kn = (kc + 1) * 64;
#pragma unroll
      for (int rj = 0; rj < 4; rj++) {
        int row = rj * 16 + sr;
        kpre[rj] = *(const bf16x8*)&Kh[(size_t)(kn + row) * DHEAD + sc];
        vpre[rj] = *(const bf16x8*)&Vh[(size_t)row * SEQ + kn + sc];
      }
    }

    if (kc <= dcn) {  // wave has live keys in this chunk
      // ---- S^T = K * Q^T ----
      f32x16 s0 = {}, s1 = {};
#pragma unroll
      for (int ds = 0; ds < 4; ds++) {
        bf16x8 kf0 = *(const bf16x8*)&Ks[cur][ql * KPAD + ds * 16 + 8 * h];
        bf16x8 kf1 = *(const bf16x8*)&Ks[cur][(32 + ql) * KPAD + ds * 16 + 8 * h];
        s0 = __builtin_amdgcn_mfma_f32_32x32x16_bf16(kf0, qf[ds], s0, 0, 0, 0);
        s1 = __builtin_amdgcn_mfma_f32_32x32x16_bf16(kf1, qf[ds], s1, 0, 0, 0);
      }
      int k0 = kc * 64;
      // ---- causal mask (diagonal chunk only) ----
      if (kc == dcn) {
#pragma unroll
        for (int r = 0; r < 16; r++) {
          int kloc = (r & 3) + 8 * (r >> 2) + 4 * h;
          if (k0 + kloc > qrow) s0[r] = -3.0e38f;
          if (k0 + 32 + kloc > qrow) s1[r] = -3.0e38f;
        }
      }
      // ---- online softmax (exp2 domain, defer-max THR=8; l_r per-lane partial) ----
      float t0[8], t1[8];
#pragma unroll
      for (int r = 0; r < 8; r++) t0[r] = fmaxf(s0[r], s0[r + 8]);
#pragma unroll
      for (int r = 0; r < 8; r++) t1[r] = fmaxf(s1[r], s1[r + 8]);
#pragma unroll
      for (int r = 0; r < 4; r++) t0[r] = fmaxf(fmaxf(t0[r], t0[r + 4]), fmaxf(t1[r], t1[r + 4]));
      float pm = fmaxf(fmaxf(t0[0], t0[1]), fmaxf(t0[2], t0[3]));
      pm = fmaxf(pm, __shfl_xor(pm, 32));
      bool grow = pm > m_r + 8.0f;
      float mnew = grow ? pm : m_r;
      float sf = grow ? __builtin_amdgcn_exp2f(m_r - mnew) : 1.0f;
      m_r = mnew;
      float rsum = 0.0f;
#pragma unroll
      for (int r = 0; r < 16; r++) { s0[r] = __builtin_amdgcn_exp2f(s0[r] - m_r); rsum += s0[r]; }
#pragma unroll
      for (int r = 0; r < 16; r++) { s1[r] = __builtin_amdgcn_exp2f(s1[r] - m_r); rsum += s1[r]; }
      l_r = l_r * sf + rsum;
      if (__ballot(grow)) {
#pragma unroll
        for (int r = 0; r < 16; r++) { o0[r] *= sf; o1[r] *= sf; }
      }
      // ---- P^T B-fragments in-register ----
      unsigned int pa0 = cvtpk_bf16(s0[0], s0[1]),   pa1 = cvtpk_bf16(s0[2], s0[3]);
      unsigned int pb0 = cvtpk_bf16(s0[4], s0[5]),   pb1 = cvtpk_bf16(s0[6], s0[7]);
      unsigned int pc0 = cvtpk_bf16(s0[8], s0[9]),   pc1 = cvtpk_bf16(s0[10], s0[11]);
      unsigned int pd0 = cvtpk_bf16(s0[12], s0[13]), pd1 = cvtpk_bf16(s0[14], s0[15]);
      unsigned int pe0 = cvtpk_bf16(s1[0], s1[1]),   pe1 = cvtpk_bf16(s1[2], s1[3]);
      unsigned int pf0 = cvtpk_bf16(s1[4], s1[5]),   pf1 = cvtpk_bf16(s1[6], s1[7]);
      unsigned int pg0 = cvtpk_bf16(s1[8], s1[9]),   pg1 = cvtpk_bf16(s1[10], s1[11]);
      unsigned int ph0 = cvtpk_bf16(s1[12], s1[13]), ph1 = cvtpk_bf16(s1[14], s1[15]);
      pl32swap(pa0, pb0); pl32swap(pa1, pb1);
      pl32swap(pc0, pd0); pl32swap(pc1, pd1);
      pl32swap(pe0, pf0); pl32swap(pe1, pf1);
      pl32swap(pg0, ph0); pl32swap(pg1, ph1);
      bf16x8 pfr[4];
      pfr[0] = __builtin_bit_cast(bf16x8, (u32x4){pa0, pa1, pb0, pb1});
      pfr[1] = __builtin_bit_cast(bf16x8, (u32x4){pc0, pc1, pd0, pd1});
      pfr[2] = __builtin_bit_cast(bf16x8, (u32x4){pe0, pe1, pf0, pf1});
      pfr[3] = __builtin_bit_cast(bf16x8, (u32x4){pg0, pg1, ph0, ph1});
      // ---- O^T += V^T * P^T ----
#pragma unroll
      for (int ks = 0; ks < 4; ks++) {
        bf16x8 vf0 = *(const bf16x8*)&Vs[cur][ql * KPAD + ks * 16 + 8 * h];
        bf16x8 vf1 = *(const bf16x8*)&Vs[cur][(32 + ql) * KPAD + ks * 16 + 8 * h];
        o0 = __builtin_amdgcn_mfma_f32_32x32x16_bf16(vf0, pfr[ks], o0, 0, 0, 0);
        o1 = __builtin_amdgcn_mfma_f32_32x32x16_bf16(vf1, pfr[ks], o1, 0, 0, 0);
      }
    }

    if (pfn) {  // write prefetched chunk into other buffer (its readers finished last iter)
#pragma unroll
      for (int rj = 0; rj < 4; rj++) {
        int row = rj * 16 + sr;
        *(bf16x8*)&Ks[cur ^ 1][row * KPAD + sc] = kpre[rj];
        *(bf16x8*)&Vs[cur ^ 1][row * KPAD + sc] = vpre[rj];
      }
    }
    __syncthreads();
  }

  // ---- epilogue: combine cross-half l, then O = O^T / l ----
  float lt = l_r + __shfl_xor(l_r, 32);
  float rl = 1.0f / lt;
  size_t obase = ((size_t)(b * SEQ + qrow)) * DMODEL + hh * DHEAD;
#pragma unroll
  for (int rg = 0; rg < 4; rg++) {
    uint2 w0, w1;
    w0.x = cvtpk_bf16(o0[4 * rg] * rl, o0[4 * rg + 1] * rl);
    w0.y = cvtpk_bf16(o0[4 * rg + 2] * rl, o0[4 * rg + 3] * rl);
    w1.x = cvtpk_bf16(o1[4 * rg] * rl, o1[4 * rg + 1] * rl);
    w1.y = cvtpk_bf16(o1[4 * rg + 2] * rl, o1[4 * rg + 3] * rl);
    *(uint2*)&Ob[obase + 8 * rg + 4 * h] = w0;
    *(uint2*)&Ob[obase + 32 + 8 * rg + 4 * h] = w1;
  }
}

// ---------------- output projection ----------------
__global__ __launch_bounds__(256) void k_gemm_out(const unsigned short* __restrict__ Ob,
                                                  const unsigned short* __restrict__ Wot,
                                                  float* __restrict__ out) {
  __shared__ unsigned short As[128 * 32];
  __shared__ unsigned short Bs[128 * 32];
  int col0 = blockIdx.x * 128;
  int brow0 = blockIdx.y * 128;
  int lane = threadIdx.x & 63, wave = threadIdx.x >> 6;
  int wr = wave >> 1, wc = wave & 1;
  f32x4 acc[4][4] = {};
  gemm_core(Ob, Wot, brow0, col0, As, Bs, acc);
#pragma unroll
  for (int i = 0; i < 4; i++)
#pragma unroll
    for (int j = 0; j < 4; j++)
#pragma unroll
      for (int r = 0; r < 4; r++) {
        int row = brow0 + wr * 64 + i * 16 + ((lane >> 4) << 2) + r;
        int c = col0 + wc * 64 + j * 16 + (lane & 15);
        out[(size_t)row * DMODEL + c] = acc[i][j][r];
      }
}

extern "C" void kernel_launch(void* const* d_in, const int* in_sizes, int n_in,
                              void* d_out, int out_size, void* d_ws, size_t ws_size,
                              hipStream_t stream) {
  const float* x  = (const float*)d_in[0];
  const float* Wq = (const float*)d_in[1];
  const float* Wk = (const float*)d_in[2];
  const float* Wv = (const float*)d_in[3];
  const float* Wo = (const float*)d_in[4];
  float* out = (float*)d_out;
  char* ws = (char*)d_ws;
  unsigned short* xb  = (unsigned short*)(ws);
  unsigned short* Wqt = (unsigned short*)(ws + (8ull << 20));
  unsigned short* Wkt = (unsigned short*)(ws + (10ull << 20));
  unsigned short* Wvt = (unsigned short*)(ws + (12ull << 20));
  unsigned short* Wot = (unsigned short*)(ws + (14ull << 20));
  unsigned short* Qb  = (unsigned short*)(ws + (16ull << 20));
  unsigned short* Kb  = (unsigned short*)(ws + (24ull << 20));
  unsigned short* Vtb = (unsigned short*)(ws + (32ull << 20));
  unsigned short* Ob  = (unsigned short*)(ws + (40ull << 20));

  k_conv_x<<<dim3(4096), dim3(256), 0, stream>>>(x, xb);
  k_trans_w<<<dim3(16, 16, 4), dim3(256), 0, stream>>>(Wq, Wk, Wv, Wo, Wqt, Wkt, Wvt, Wot);
  k_gemm_qkv<<<dim3(24, 32), dim3(256), 0, stream>>>(xb, Wqt, Wkt, Wvt, Qb, Kb, Vtb);
  k_attn<<<dim3(1024), dim3(128), 0, stream>>>(Qb, Kb, Vtb, Ob);
  k_gemm_out<<<dim3(8, 32), dim3(256), 0, stream>>>(Ob, Wot, out);
}